// Round 8
// baseline (459.263 us; speedup 1.0000x reference)
//
#include <hip/hip_runtime.h>
#include <hip/hip_cooperative_groups.h>

#define N_NODES 100000
#define N_EDGES 1600000
#define D 128

#define NB 782                  // coarse buckets: 128 rows each
#define SLOT 2560               // slots per bucket (mean 2046 + 11 sigma slack)
#define GRID 512
#define CHUNK 3125              // N_EDGES / GRID
#define NTILES 6250             // N_NODES / 16 row-tiles for gemm

// workspace layout (bytes)
#define WB_OFF     0u           // 32 KB bf16 W
#define HWB_OFF    65536u       // 25.6 MB bf16 HW
#define BCNT_OFF   25665536u    // 782 ints (pad to 4 KB)
#define EPACK0_OFF 25669632u    // NB*SLOT int2 = 16,015,360 B
// end ~41.7 MB

typedef unsigned int uint;
typedef __attribute__((ext_vector_type(4))) float f32x4;
typedef __attribute__((ext_vector_type(8))) short bf16x8;

namespace cg = cooperative_groups;

__device__ __forceinline__ unsigned short f2bf(float x) {
    uint u = __float_as_uint(x);
    uint r = u + 0x7fffu + ((u >> 16) & 1u);   // round-to-nearest-even
    return (unsigned short)(r >> 16);
}

__device__ __forceinline__ void acc8(float acc[8], uint4 q, float v) {
    acc[0] = fmaf(v, __uint_as_float(q.x << 16),         acc[0]);
    acc[1] = fmaf(v, __uint_as_float(q.x & 0xffff0000u), acc[1]);
    acc[2] = fmaf(v, __uint_as_float(q.y << 16),         acc[2]);
    acc[3] = fmaf(v, __uint_as_float(q.y & 0xffff0000u), acc[3]);
    acc[4] = fmaf(v, __uint_as_float(q.z << 16),         acc[4]);
    acc[5] = fmaf(v, __uint_as_float(q.z & 0xffff0000u), acc[5]);
    acc[6] = fmaf(v, __uint_as_float(q.w << 16),         acc[6]);
    acc[7] = fmaf(v, __uint_as_float(q.w & 0xffff0000u), acc[7]);
}

// LDS union: stages are sequential, separated by __syncthreads/grid.sync
union SMem {
    unsigned short gtile[4][2048];                                   // 16 KB: per-wave 16x128 bf16 epilogue
    struct { int srows[CHUNK]; int hist[NB]; int cur[NB]; } bk;      // 18.8 KB
    struct { int scol[SLOT]; float sval[SLOT];
             int hist[128], sc[128], cur[128], rstart[128]; } sp;    // 22.5 KB
};

__global__ __launch_bounds__(256, 2) void k_fused(const float* __restrict__ H,
                                                  const float* __restrict__ vals,
                                                  const float* __restrict__ W,
                                                  const int* __restrict__ rows,
                                                  const int* __restrict__ cols,
                                                  unsigned short* __restrict__ Wb,
                                                  unsigned short* __restrict__ HWb,
                                                  int* __restrict__ bcnt,
                                                  int2* __restrict__ epack0,
                                                  float* __restrict__ out) {
    __shared__ SMem sm;
    cg::grid_group grid = cg::this_grid();
    const int tid = threadIdx.x;
    const int b   = blockIdx.x;

    // ================= stage A: cast W -> bf16, zero bcnt =================
    {
        int i = b * 256 + tid;
        if (i < D * D) Wb[i] = f2bf(W[i]);
        if (b == 64) {
            for (int j = tid; j < NB; j += 256) bcnt[j] = 0;
        }
    }
    __threadfence();
    grid.sync();

    // ================= stage B1: HWb = bf16(H @ W^T), MFMA ================
    const int wave = tid >> 6;
    const int lane = tid & 63;
    const int m    = lane & 15;
    const int quad = lane >> 4;

    for (int it = 0; it < 4; ++it) {
        const int tile  = it * (GRID * 4) + b * 4 + wave;
        const bool valid = (tile < NTILES);
        if (valid) {
            const int rowbase = tile * 16;
            f32x4 acc[8];
            #pragma unroll
            for (int nt = 0; nt < 8; ++nt) acc[nt] = (f32x4){0.f, 0.f, 0.f, 0.f};

            const float* hrow = H + (size_t)(rowbase + m) * D;
            #pragma unroll
            for (int ks = 0; ks < 4; ++ks) {
                const int k0 = ks * 32 + quad * 8;
                float4 a0 = *(const float4*)(hrow + k0);
                float4 a1 = *(const float4*)(hrow + k0 + 4);
                bf16x8 afr;
                afr[0] = (short)f2bf(a0.x); afr[1] = (short)f2bf(a0.y);
                afr[2] = (short)f2bf(a0.z); afr[3] = (short)f2bf(a0.w);
                afr[4] = (short)f2bf(a1.x); afr[5] = (short)f2bf(a1.y);
                afr[6] = (short)f2bf(a1.z); afr[7] = (short)f2bf(a1.w);
                #pragma unroll
                for (int nt = 0; nt < 8; ++nt) {
                    bf16x8 bfr = *(const bf16x8*)(Wb + (size_t)(nt * 16 + m) * D + k0);
                    acc[nt] = __builtin_amdgcn_mfma_f32_16x16x32_bf16(afr, bfr, acc[nt], 0, 0, 0);
                }
            }
            // scatter acc into per-wave LDS tile (16 rows x 128 cols bf16)
            unsigned short* lds = sm.gtile[wave];
            #pragma unroll
            for (int nt = 0; nt < 8; ++nt)
                #pragma unroll
                for (int r = 0; r < 4; ++r)
                    lds[(quad * 4 + r) * 128 + nt * 16 + m] = f2bf(acc[nt][r]);
        }
        __syncthreads();
        if (valid) {
            const int rowbase = tile * 16;
            const unsigned short* lds = sm.gtile[wave];
            #pragma unroll
            for (int c = 0; c < 4; ++c) {
                int chunk = c * 64 + lane;          // 0..255 of 16B chunks
                int row   = chunk >> 4;             // 0..15
                int off   = chunk & 15;             // 16B chunk within row
                uint4 q = *(const uint4*)(lds + row * 128 + off * 8);
                *(uint4*)(HWb + (size_t)(rowbase + row) * D + off * 8) = q;
            }
        }
        __syncthreads();
    }

    // ================= stage B2: coarse bucket =================
    {
        const int e0 = b * CHUNK;
        for (int i = tid; i < NB; i += 256) sm.bk.hist[i] = 0;
        __syncthreads();
        for (int i = tid; i < CHUNK; i += 256) {
            int r = rows[e0 + i];
            sm.bk.srows[i] = r;
            atomicAdd(&sm.bk.hist[r >> 7], 1);
        }
        __syncthreads();
        for (int bb = tid; bb < NB; bb += 256) {
            int c = sm.bk.hist[bb];
            int base = (c > 0) ? atomicAdd(&bcnt[bb], c) : 0;
            sm.bk.cur[bb] = bb * SLOT + base;
        }
        __syncthreads();
        for (int i = tid; i < CHUNK; i += 256) {
            int r = sm.bk.srows[i];
            int p = atomicAdd(&sm.bk.cur[r >> 7], 1);
            epack0[p] = make_int2(((r & 127) << 17) | cols[e0 + i],
                                  __float_as_int(vals[e0 + i]));
        }
    }
    __threadfence();
    grid.sync();

    // ========== stage C: fused sort + SpMM + ReLU (R6 form, unroll-4) ==========
    const int lane16 = tid & 15;
    const int group  = tid >> 4;

    for (int bb = b; bb < NB; bb += GRID) {
        const int base = bb * SLOT;
        const int n_e  = bcnt[bb];

        if (tid < 128) sm.sp.hist[tid] = 0;
        __syncthreads();

        for (int i = tid; i < n_e; i += 256)
            atomicAdd(&sm.sp.hist[epack0[base + i].x >> 17], 1);
        __syncthreads();

        // exclusive scan of hist[128]
        if (tid < 128) sm.sp.sc[tid] = sm.sp.hist[tid];
        __syncthreads();
        #pragma unroll
        for (int off = 1; off < 128; off <<= 1) {
            int t = (tid < 128 && tid >= off) ? sm.sp.sc[tid - off] : 0;
            __syncthreads();
            if (tid < 128) sm.sp.sc[tid] += t;
            __syncthreads();
        }
        if (tid < 128) {
            int ex = sm.sp.sc[tid] - sm.sp.hist[tid];
            sm.sp.rstart[tid] = ex;
            sm.sp.cur[tid]    = ex;
        }
        __syncthreads();

        // place sorted (col,val) into LDS
        for (int i = tid; i < n_e; i += 256) {
            int2 e  = epack0[base + i];
            int  lr = e.x >> 17;
            int  p  = atomicAdd(&sm.sp.cur[lr], 1);
            sm.sp.scol[p] = e.x & 0x1FFFF;
            sm.sp.sval[p] = __int_as_float(e.y);
        }
        __syncthreads();

        // gather: group owns rows group*8 .. group*8+7
        #pragma unroll
        for (int rr = 0; rr < 8; ++rr) {
            const int lr  = group * 8 + rr;
            const int row = bb * 128 + lr;
            if (row >= N_NODES) continue;
            const int s  = sm.sp.rstart[lr];
            const int e_ = sm.sp.cur[lr];

            float acc[8];
            #pragma unroll
            for (int c = 0; c < 8; ++c) acc[c] = 0.f;

            int j = s;
            for (; j + 3 < e_; j += 4) {
                int   c0 = sm.sp.scol[j],     c1 = sm.sp.scol[j + 1];
                int   c2 = sm.sp.scol[j + 2], c3 = sm.sp.scol[j + 3];
                float v0 = sm.sp.sval[j],     v1 = sm.sp.sval[j + 1];
                float v2 = sm.sp.sval[j + 2], v3 = sm.sp.sval[j + 3];
                uint4 q0 = ((const uint4*)(HWb + (size_t)c0 * D))[lane16];
                uint4 q1 = ((const uint4*)(HWb + (size_t)c1 * D))[lane16];
                uint4 q2 = ((const uint4*)(HWb + (size_t)c2 * D))[lane16];
                uint4 q3 = ((const uint4*)(HWb + (size_t)c3 * D))[lane16];
                acc8(acc, q0, v0); acc8(acc, q1, v1);
                acc8(acc, q2, v2); acc8(acc, q3, v3);
            }
            for (; j < e_; ++j) {
                int   c = sm.sp.scol[j];
                float v = sm.sp.sval[j];
                uint4 q = ((const uint4*)(HWb + (size_t)c * D))[lane16];
                acc8(acc, q, v);
            }

            float4 o0 = make_float4(fmaxf(acc[0], 0.f), fmaxf(acc[1], 0.f),
                                    fmaxf(acc[2], 0.f), fmaxf(acc[3], 0.f));
            float4 o1 = make_float4(fmaxf(acc[4], 0.f), fmaxf(acc[5], 0.f),
                                    fmaxf(acc[6], 0.f), fmaxf(acc[7], 0.f));
            ((float4*)out)[row * 32 + lane16 * 2]     = o0;
            ((float4*)out)[row * 32 + lane16 * 2 + 1] = o1;
        }
        __syncthreads();   // protect LDS union before next bucket iteration
    }
}

// ---------------------------------------------------------------------------
extern "C" void kernel_launch(void* const* d_in, const int* in_sizes, int n_in,
                              void* d_out, int out_size, void* d_ws, size_t ws_size,
                              hipStream_t stream) {
    const float* H    = (const float*)d_in[0];
    const float* vals = (const float*)d_in[1];
    const float* W    = (const float*)d_in[2];
    const int*   rows = (const int*)d_in[3];
    const int*   cols = (const int*)d_in[4];
    float* outp = (float*)d_out;

    char* ws = (char*)d_ws;
    unsigned short* Wb     = (unsigned short*)(ws + WB_OFF);
    unsigned short* HWb    = (unsigned short*)(ws + HWB_OFF);
    int*            bcnt   = (int*)(ws + BCNT_OFF);
    int2*           epack0 = (int2*)(ws + EPACK0_OFF);

    void* kargs[] = {(void*)&H, (void*)&vals, (void*)&W, (void*)&rows, (void*)&cols,
                     (void*)&Wb, (void*)&HWb, (void*)&bcnt, (void*)&epack0, (void*)&outp};
    hipLaunchCooperativeKernel((void*)k_fused, dim3(GRID), dim3(256), kargs, 0, stream);
}

// Round 9
// 257.926 us; speedup vs baseline: 1.7806x; 1.7806x over previous
//
#include <hip/hip_runtime.h>

#define N_NODES 100000
#define N_EDGES 1600000
#define D 128

#define NB 1563                 // 64-row buckets: 1562*64=99968 + partial 32
#define SLOT 1280               // slots per bucket (mean 1024, sigma 32 -> +8 sigma)
#define CHUNK 6400              // edges per bucket_coarse block
#define NBLK_BUCKET 250         // 250 * 6400 = 1.6M
#define NTILES 6250             // N_NODES/16 gemm row-tiles

// workspace layout (bytes)
#define WB_OFF     0u           // 32 KB bf16 W
#define HWB_OFF    65536u       // 25.6 MB bf16 HW
#define BCNT_OFF   25665536u    // 1563 ints (pad 8 KB)
#define EPACK0_OFF 25673728u    // NB*SLOT int2 = 16,005,120 B
// end ~41.7 MB

typedef unsigned int uint;
typedef __attribute__((ext_vector_type(4))) float f32x4;
typedef __attribute__((ext_vector_type(8))) short bf16x8;

__device__ __forceinline__ unsigned short f2bf(float x) {
    uint u = __float_as_uint(x);
    uint r = u + 0x7fffu + ((u >> 16) & 1u);   // round-to-nearest-even
    return (unsigned short)(r >> 16);
}

__device__ __forceinline__ void acc8(float acc[8], uint4 q, float v) {
    acc[0] = fmaf(v, __uint_as_float(q.x << 16),         acc[0]);
    acc[1] = fmaf(v, __uint_as_float(q.x & 0xffff0000u), acc[1]);
    acc[2] = fmaf(v, __uint_as_float(q.y << 16),         acc[2]);
    acc[3] = fmaf(v, __uint_as_float(q.y & 0xffff0000u), acc[3]);
    acc[4] = fmaf(v, __uint_as_float(q.z << 16),         acc[4]);
    acc[5] = fmaf(v, __uint_as_float(q.z & 0xffff0000u), acc[5]);
    acc[6] = fmaf(v, __uint_as_float(q.w << 16),         acc[6]);
    acc[7] = fmaf(v, __uint_as_float(q.w & 0xffff0000u), acc[7]);
}

// ---------------------------------------------------------------------------
// blocks 0..63 cast W->bf16; blocks 64..70 zero bcnt (saves a memset launch)
__global__ void k_cast_zero(const float* __restrict__ W, unsigned short* __restrict__ Wb,
                            int* __restrict__ bcnt) {
    int b = blockIdx.x;
    if (b < 64) {
        int i = b * 256 + threadIdx.x;
        Wb[i] = f2bf(W[i]);
    } else {
        int j = (b - 64) * 256 + threadIdx.x;
        if (j < NB) bcnt[j] = 0;
    }
}

// ---------------------------------------------------------------------------
// HWb = bf16( H @ W^T ) via mfma_f32_16x16x32_bf16. One wave per 16 rows.
__global__ __launch_bounds__(256) void k_gemm_mfma(const float* __restrict__ H,
                                                   const unsigned short* __restrict__ Wb,
                                                   unsigned short* __restrict__ HWb) {
    const int wave = threadIdx.x >> 6;
    const int lane = threadIdx.x & 63;
    const int rowtile = blockIdx.x * 4 + wave;
    if (rowtile >= NTILES) return;
    const int rowbase = rowtile * 16;
    const int m    = lane & 15;
    const int quad = lane >> 4;

    f32x4 acc[8];
    #pragma unroll
    for (int nt = 0; nt < 8; ++nt) acc[nt] = (f32x4){0.f, 0.f, 0.f, 0.f};

    const float* hrow = H + (size_t)(rowbase + m) * D;

    #pragma unroll
    for (int ks = 0; ks < 4; ++ks) {
        const int k0 = ks * 32 + quad * 8;
        float4 a0 = *(const float4*)(hrow + k0);
        float4 a1 = *(const float4*)(hrow + k0 + 4);
        bf16x8 afr;
        afr[0] = (short)f2bf(a0.x); afr[1] = (short)f2bf(a0.y);
        afr[2] = (short)f2bf(a0.z); afr[3] = (short)f2bf(a0.w);
        afr[4] = (short)f2bf(a1.x); afr[5] = (short)f2bf(a1.y);
        afr[6] = (short)f2bf(a1.z); afr[7] = (short)f2bf(a1.w);
        #pragma unroll
        for (int nt = 0; nt < 8; ++nt) {
            bf16x8 bfr = *(const bf16x8*)(Wb + (size_t)(nt * 16 + m) * D + k0);
            acc[nt] = __builtin_amdgcn_mfma_f32_16x16x32_bf16(afr, bfr, acc[nt], 0, 0, 0);
        }
    }

    #pragma unroll
    for (int nt = 0; nt < 8; ++nt) {
        #pragma unroll
        for (int r = 0; r < 4; ++r) {
            int orow = rowbase + quad * 4 + r;
            HWb[(size_t)orow * D + nt * 16 + m] = f2bf(acc[nt][r]);
        }
    }
}

// ---------------------------------------------------------------------------
// Coarse bucket by row>>6 (64-row buckets). Block-local LDS count, one global
// atomic span reservation per (block,bucket), dense-in-time placement.
// epack0 entry: x = (local_row<<17) | col   (local_row 6 bits, col < 2^17)
__global__ __launch_bounds__(256) void k_bucket_coarse(const int* __restrict__ rows,
                                                       const int* __restrict__ cols,
                                                       const float* __restrict__ vals,
                                                       int* __restrict__ bcnt,
                                                       int2* __restrict__ epack0) {
    __shared__ int srows[CHUNK];        // 25.6 KB
    __shared__ int hist[NB];            // 6.25 KB
    __shared__ int cur[NB];             // 6.25 KB
    const int tid = threadIdx.x;
    const int e0  = blockIdx.x * CHUNK;

    for (int b = tid; b < NB; b += 256) hist[b] = 0;
    __syncthreads();

    for (int i = tid; i < CHUNK; i += 256) {
        int r = rows[e0 + i];
        srows[i] = r;
        atomicAdd(&hist[r >> 6], 1);
    }
    __syncthreads();

    for (int b = tid; b < NB; b += 256) {
        int c = hist[b];
        int base = (c > 0) ? atomicAdd(&bcnt[b], c) : 0;
        cur[b] = b * SLOT + base;
    }
    __syncthreads();

    for (int i = tid; i < CHUNK; i += 256) {
        int r = srows[i];
        int p = atomicAdd(&cur[r >> 6], 1);
        epack0[p] = make_int2(((r & 63) << 17) | cols[e0 + i],
                              __float_as_int(vals[e0 + i]));
    }
}

// ---------------------------------------------------------------------------
// Fused sort + SpMM + ReLU: one block per 64-row bucket (1563 blocks ->
// ~6 blocks/CU vs R6's 3: double the resident waves on a latency-bound
// gather). LDS counting-sort by local row, then 16-lane groups gather for
// 4 consecutive rows each, unrolled x4 for MLP.
__global__ __launch_bounds__(256) void k_spmm_fused(const int* __restrict__ bcnt,
                                                    const int2* __restrict__ epack0,
                                                    const unsigned short* __restrict__ HWb,
                                                    float* __restrict__ out) {
    __shared__ int   scol[SLOT];        // 5.12 KB
    __shared__ float sval[SLOT];        // 5.12 KB
    __shared__ int hist[64];
    __shared__ int sc[64];
    __shared__ int cur[64];
    __shared__ int rstart[64];
    const int tid  = threadIdx.x;
    const int b    = blockIdx.x;
    const int base = b * SLOT;
    const int n_e  = bcnt[b];

    if (tid < 64) hist[tid] = 0;
    __syncthreads();

    for (int i = tid; i < n_e; i += 256)
        atomicAdd(&hist[epack0[base + i].x >> 17], 1);
    __syncthreads();

    // exclusive scan of hist[64]
    if (tid < 64) sc[tid] = hist[tid];
    __syncthreads();
    #pragma unroll
    for (int off = 1; off < 64; off <<= 1) {
        int t = (tid < 64 && tid >= off) ? sc[tid - off] : 0;
        __syncthreads();
        if (tid < 64) sc[tid] += t;
        __syncthreads();
    }
    if (tid < 64) {
        int ex = sc[tid] - hist[tid];
        rstart[tid] = ex;
        cur[tid]    = ex;
    }
    __syncthreads();

    // place sorted (col,val) into LDS (re-read epack0: L2-warm)
    for (int i = tid; i < n_e; i += 256) {
        int2 e  = epack0[base + i];
        int  lr = e.x >> 17;
        int  p  = atomicAdd(&cur[lr], 1);
        scol[p] = e.x & 0x1FFFF;
        sval[p] = __int_as_float(e.y);
    }
    __syncthreads();

    // gather: group (tid>>4) owns rows group*4 .. group*4+3
    const int lane  = tid & 15;
    const int group = tid >> 4;

    #pragma unroll
    for (int rr = 0; rr < 4; ++rr) {
        const int lr  = group * 4 + rr;
        const int row = b * 64 + lr;
        if (row >= N_NODES) continue;
        const int s  = rstart[lr];
        const int e_ = cur[lr];

        float acc[8];
        #pragma unroll
        for (int c = 0; c < 8; ++c) acc[c] = 0.f;

        int j = s;
        for (; j + 3 < e_; j += 4) {
            int   c0 = scol[j],     c1 = scol[j + 1], c2 = scol[j + 2], c3 = scol[j + 3];
            float v0 = sval[j],     v1 = sval[j + 1], v2 = sval[j + 2], v3 = sval[j + 3];
            uint4 q0 = ((const uint4*)(HWb + (size_t)c0 * D))[lane];
            uint4 q1 = ((const uint4*)(HWb + (size_t)c1 * D))[lane];
            uint4 q2 = ((const uint4*)(HWb + (size_t)c2 * D))[lane];
            uint4 q3 = ((const uint4*)(HWb + (size_t)c3 * D))[lane];
            acc8(acc, q0, v0); acc8(acc, q1, v1);
            acc8(acc, q2, v2); acc8(acc, q3, v3);
        }
        for (; j < e_; ++j) {
            int   c = scol[j];
            float v = sval[j];
            uint4 q = ((const uint4*)(HWb + (size_t)c * D))[lane];
            acc8(acc, q, v);
        }

        float4 o0 = make_float4(fmaxf(acc[0], 0.f), fmaxf(acc[1], 0.f),
                                fmaxf(acc[2], 0.f), fmaxf(acc[3], 0.f));
        float4 o1 = make_float4(fmaxf(acc[4], 0.f), fmaxf(acc[5], 0.f),
                                fmaxf(acc[6], 0.f), fmaxf(acc[7], 0.f));
        ((float4*)out)[row * 32 + lane * 2]     = o0;
        ((float4*)out)[row * 32 + lane * 2 + 1] = o1;
    }
}

// ---------------------------------------------------------------------------
extern "C" void kernel_launch(void* const* d_in, const int* in_sizes, int n_in,
                              void* d_out, int out_size, void* d_ws, size_t ws_size,
                              hipStream_t stream) {
    const float* H    = (const float*)d_in[0];
    const float* vals = (const float*)d_in[1];
    const float* W    = (const float*)d_in[2];
    const int*   rows = (const int*)d_in[3];
    const int*   cols = (const int*)d_in[4];
    float* out = (float*)d_out;

    char* ws = (char*)d_ws;
    unsigned short* Wb     = (unsigned short*)(ws + WB_OFF);
    unsigned short* HWb    = (unsigned short*)(ws + HWB_OFF);
    int*            bcnt   = (int*)(ws + BCNT_OFF);
    int2*           epack0 = (int2*)(ws + EPACK0_OFF);

    // cast W + zero bcnt (one launch)
    k_cast_zero<<<64 + (NB + 255) / 256, 256, 0, stream>>>(W, Wb, bcnt);

    // dense path: HWb = bf16(H @ W^T), MFMA
    k_gemm_mfma<<<(NTILES + 3) / 4, 256, 0, stream>>>(H, Wb, HWb);

    // coarse bucket, then fused sort + SpMM + ReLU
    k_bucket_coarse<<<NBLK_BUCKET, 256, 0, stream>>>(rows, cols, vals, bcnt, epack0);
    k_spmm_fused<<<NB, 256, 0, stream>>>(bcnt, epack0, HWb, out);
}